// Round 1
// baseline (216.942 us; speedup 1.0000x reference)
//
#include <hip/hip_runtime.h>
#include <hip/hip_bf16.h>
#include <cstdint>

typedef __attribute__((ext_vector_type(8))) __bf16 bf16x8;
typedef __attribute__((ext_vector_type(4))) float f32x4;

#define DM 1024
#define NH 16
#define DH 64
#define S_LEN 2048
#define BATCH 2

__device__ __forceinline__ ushort f2bf(float f) {
  union { float f; uint32_t u; } v; v.f = f;
  uint32_t u = v.u;
  uint32_t r = (u + 0x7fffu + ((u >> 16) & 1u)) >> 16;
  return (ushort)r;
}
__device__ __forceinline__ float bf2f(ushort h) {
  union { uint32_t u; float f; } v; v.u = ((uint32_t)h) << 16;
  return v.f;
}

// ---------------- cast f32 -> bf16 ----------------
__global__ void cast_f32_bf16(const float* __restrict__ src, ushort* __restrict__ dst, int n4) {
  for (int i = blockIdx.x * blockDim.x + threadIdx.x; i < n4; i += gridDim.x * blockDim.x) {
    float4 v = ((const float4*)src)[i];
    ushort4 o;
    o.x = f2bf(v.x); o.y = f2bf(v.y); o.z = f2bf(v.z); o.w = f2bf(v.w);
    ((ushort4*)dst)[i] = o;
  }
}

// ---------------- GEMM: C[M,N] = A[M,K] * B[N,K]^T  (bf16 in, f32 acc) ----------------
// 128x128 tile, BK=32, 4 waves (2x2), each wave 64x64 (4x4 frags of 16x16)
template<int WRITE_BF16>
__global__ __launch_bounds__(256) void gemm_bt(
    const ushort* __restrict__ A, const ushort* __restrict__ B,
    void* __restrict__ Cv, int M, int N, int K)
{
  __shared__ ushort As[128][40];
  __shared__ ushort Bs[128][40];
  const int t = threadIdx.x;
  const int w = t >> 6, lane = t & 63;
  const int wm = w >> 1, wn = w & 1;
  const int lr = lane & 15, lk = lane >> 4;
  const int m0 = blockIdx.y * 128, n0 = blockIdx.x * 128;

  f32x4 acc[4][4];
#pragma unroll
  for (int m = 0; m < 4; m++)
#pragma unroll
    for (int n = 0; n < 4; n++) acc[m][n] = (f32x4)(0.0f);

  for (int k0 = 0; k0 < K; k0 += 32) {
#pragma unroll
    for (int p = 0; p < 2; p++) {
      int c = t + p * 256;
      int row = c >> 2;
      int col = (c & 3) * 8;
      *(uint4*)&As[row][col] = *(const uint4*)&A[(size_t)(m0 + row) * K + k0 + col];
      *(uint4*)&Bs[row][col] = *(const uint4*)&B[(size_t)(n0 + row) * K + k0 + col];
    }
    __syncthreads();
    bf16x8 af[4], bfr[4];
#pragma unroll
    for (int m = 0; m < 4; m++) af[m]  = *(const bf16x8*)&As[wm * 64 + m * 16 + lr][lk * 8];
#pragma unroll
    for (int n = 0; n < 4; n++) bfr[n] = *(const bf16x8*)&Bs[wn * 64 + n * 16 + lr][lk * 8];
#pragma unroll
    for (int m = 0; m < 4; m++)
#pragma unroll
      for (int n = 0; n < 4; n++)
        acc[m][n] = __builtin_amdgcn_mfma_f32_16x16x32_bf16(af[m], bfr[n], acc[m][n], 0, 0, 0);
    __syncthreads();
  }

#pragma unroll
  for (int m = 0; m < 4; m++) {
    int row = m0 + wm * 64 + m * 16 + lk * 4;
#pragma unroll
    for (int n = 0; n < 4; n++) {
      int col = n0 + wn * 64 + n * 16 + lr;
#pragma unroll
      for (int r = 0; r < 4; r++) {
        float val = acc[m][n][r];
        if (WRITE_BF16) ((ushort*)Cv)[(size_t)(row + r) * N + col] = f2bf(val);
        else            ((float*)Cv)[(size_t)(row + r) * N + col] = val;
      }
    }
  }
}

// ---------------- RoPE on q,k + repack to (BH, S, 64); scale folded into Q ----------------
__global__ void rope_qk(const ushort* __restrict__ qkv, ushort* __restrict__ Qh, ushort* __restrict__ Kh) {
  int idx = blockIdx.x * 256 + threadIdx.x;   // 2^21 total
  int i = idx & 31;
  int h = (idx >> 5) & 15;
  int s = (idx >> 9) & 2047;
  int b = idx >> 20;
  // inv_freq = 10000^(-i/32)
  float inv = expf(-(float)i * (9.210340371976184f / 32.0f));
  float ang = (float)s * inv;
  float sn, cs;
  sincosf(ang, &sn, &cs);
  size_t base = ((size_t)(b * S_LEN + s)) * 3072 + h * 64 + 2 * i;
  float qr = bf2f(qkv[base]),        qi = bf2f(qkv[base + 1]);
  float kr = bf2f(qkv[base + 1024]), ki = bf2f(qkv[base + 1025]);
  float oqr = qr * cs - qi * sn, oqi = qr * sn + qi * cs;
  float okr = kr * cs - ki * sn, oki = kr * sn + ki * cs;
  const float scale = 0.125f;  // D^-0.5
  size_t ob = ((size_t)((b * NH + h) * S_LEN + s)) * 64 + 2 * i;
  Qh[ob] = f2bf(oqr * scale); Qh[ob + 1] = f2bf(oqi * scale);
  Kh[ob] = f2bf(okr);         Kh[ob + 1] = f2bf(oki);
}

// ---------------- V: (b,s,h,d) slice of qkv -> Vt (BH, 64, S) ----------------
__global__ __launch_bounds__(256) void transpose_v(const ushort* __restrict__ qkv, ushort* __restrict__ Vt) {
  __shared__ ushort tile[64][72];
  int st = blockIdx.x;          // s-tile (64 rows)
  int bh = blockIdx.y;
  int b = bh >> 4, h = bh & 15;
  int t = threadIdx.x;
#pragma unroll
  for (int p = 0; p < 2; p++) {
    int c = t + p * 256;
    int srow = c >> 3;
    int d8 = (c & 7) * 8;
    *(uint4*)&tile[srow][d8] =
        *(const uint4*)&qkv[((size_t)(b * S_LEN + st * 64 + srow)) * 3072 + 2048 + h * 64 + d8];
  }
  __syncthreads();
#pragma unroll
  for (int p = 0; p < 2; p++) {
    int c = t + p * 256;
    int d = c >> 3;
    int s8 = (c & 7) * 8;
    ushort tmp[8];
#pragma unroll
    for (int j = 0; j < 8; j++) tmp[j] = tile[s8 + j][d];
    *(uint4*)&Vt[((size_t)(bh * 64 + d)) * S_LEN + st * 64 + s8] = *(uint4*)tmp;
  }
}

// ---------------- causal flash attention ----------------
// grid (S/64 qtiles, BH). 4 waves/block, wave w owns 16 q-rows.
__global__ __launch_bounds__(256) void flash_attn(
    const ushort* __restrict__ Qh, const ushort* __restrict__ Kh, const ushort* __restrict__ Vt,
    ushort* __restrict__ O)
{
  __shared__ ushort Ks[64][72];     // [key][d]
  __shared__ ushort Vs[64][72];     // [d][key]  (from Vt)
  __shared__ ushort Ps[4][16][72];  // per wave: [qrow][key]
  const int qt = blockIdx.x;
  const int bh = blockIdx.y;
  const int t = threadIdx.x, w = t >> 6, lane = t & 63;
  const int lr = lane & 15, lk = lane >> 4;

  bf16x8 qf[2];
  {
    size_t qbase = ((size_t)bh * S_LEN + qt * 64 + w * 16 + lr) * 64;
    qf[0] = *(const bf16x8*)&Qh[qbase + lk * 8];
    qf[1] = *(const bf16x8*)&Qh[qbase + 32 + lk * 8];
  }
  f32x4 oacc[4];
#pragma unroll
  for (int n = 0; n < 4; n++) oacc[n] = (f32x4)(0.0f);
  float mrow[4], lsum[4];
#pragma unroll
  for (int r = 0; r < 4; r++) { mrow[r] = -1e30f; lsum[r] = 0.0f; }

  const int q_lo = qt * 64 + w * 16;

  for (int jt = 0; jt <= qt; ++jt) {
#pragma unroll
    for (int p = 0; p < 2; p++) {
      int c = t + p * 256;
      int row = c >> 3, c8 = (c & 7) * 8;
      *(uint4*)&Ks[row][c8] = *(const uint4*)&Kh[((size_t)bh * S_LEN + jt * 64 + row) * 64 + c8];
      *(uint4*)&Vs[row][c8] = *(const uint4*)&Vt[((size_t)(bh * 64 + row)) * S_LEN + jt * 64 + c8];
    }
    __syncthreads();

    f32x4 sc[4];
#pragma unroll
    for (int n = 0; n < 4; n++) {
      sc[n] = (f32x4)(0.0f);
      bf16x8 kf0 = *(const bf16x8*)&Ks[n * 16 + lr][lk * 8];
      bf16x8 kf1 = *(const bf16x8*)&Ks[n * 16 + lr][32 + lk * 8];
      sc[n] = __builtin_amdgcn_mfma_f32_16x16x32_bf16(qf[0], kf0, sc[n], 0, 0, 0);
      sc[n] = __builtin_amdgcn_mfma_f32_16x16x32_bf16(qf[1], kf1, sc[n], 0, 0, 0);
    }

    if (jt == qt) {
#pragma unroll
      for (int n = 0; n < 4; n++)
#pragma unroll
        for (int r = 0; r < 4; r++) {
          int qrow = q_lo + lk * 4 + r;
          int kcol = jt * 64 + n * 16 + lr;
          if (kcol > qrow) sc[n][r] = -1e30f;
        }
    }

    float alpha[4];
#pragma unroll
    for (int r = 0; r < 4; r++) {
      float v = fmaxf(fmaxf(sc[0][r], sc[1][r]), fmaxf(sc[2][r], sc[3][r]));
#pragma unroll
      for (int off = 1; off < 16; off <<= 1) v = fmaxf(v, __shfl_xor(v, off, 64));
      float mn = fmaxf(mrow[r], v);
      alpha[r] = __expf(mrow[r] - mn);
      mrow[r] = mn;
    }
    float rsum[4] = {0.f, 0.f, 0.f, 0.f};
#pragma unroll
    for (int n = 0; n < 4; n++)
#pragma unroll
      for (int r = 0; r < 4; r++) {
        float p = __expf(sc[n][r] - mrow[r]);
        rsum[r] += p;
        Ps[w][lk * 4 + r][n * 16 + lr] = f2bf(p);
      }
#pragma unroll
    for (int r = 0; r < 4; r++) {
      float v = rsum[r];
#pragma unroll
      for (int off = 1; off < 16; off <<= 1) v += __shfl_xor(v, off, 64);
      lsum[r] = lsum[r] * alpha[r] + v;
#pragma unroll
      for (int n = 0; n < 4; n++) oacc[n][r] *= alpha[r];
    }

#pragma unroll
    for (int n = 0; n < 4; n++)
#pragma unroll
      for (int kk = 0; kk < 2; kk++) {
        bf16x8 pf = *(const bf16x8*)&Ps[w][lr][kk * 32 + lk * 8];
        bf16x8 vf = *(const bf16x8*)&Vs[n * 16 + lr][kk * 32 + lk * 8];
        oacc[n] = __builtin_amdgcn_mfma_f32_16x16x32_bf16(pf, vf, oacc[n], 0, 0, 0);
      }
    __syncthreads();
  }

  const int b = bh >> 4, h = bh & 15;
#pragma unroll
  for (int n = 0; n < 4; n++)
#pragma unroll
    for (int r = 0; r < 4; r++) {
      int srow = qt * 64 + w * 16 + lk * 4 + r;
      float val = oacc[n][r] / lsum[r];
      O[((size_t)(b * S_LEN + srow)) * 1024 + h * 64 + n * 16 + lr] = f2bf(val);
    }
}

extern "C" void kernel_launch(void* const* d_in, const int* in_sizes, int n_in,
                              void* d_out, int out_size, void* d_ws, size_t ws_size,
                              hipStream_t stream) {
  const float* x     = (const float*)d_in[0];
  const float* w_qkv = (const float*)d_in[2];
  const float* w_out = (const float*)d_in[3];
  float* out = (float*)d_out;

  char* ws = (char*)d_ws;
  ushort* xb    = (ushort*)(ws);                          //  8 MB: (4096,1024) bf16
  ushort* wqkvb = (ushort*)(ws + 8388608);                //  6 MB: (3072,1024) bf16
  ushort* woutb = (ushort*)(ws + 14680064);               //  2 MB: (1024,1024) bf16
  ushort* qkvb  = (ushort*)(ws + 16777216);               // 24 MB: (4096,3072) bf16
  ushort* Qh    = (ushort*)(ws + 41943040);               //  8 MB: (32,2048,64)
  ushort* Kh    = (ushort*)(ws + 50331648);               //  8 MB
  ushort* Vt    = (ushort*)(ws + 58720256);               //  8 MB: (32,64,2048)
  ushort* Ob    = (ushort*)(ws + 67108864);               //  8 MB: (4096,1024) bf16

  // 1. casts
  cast_f32_bf16<<<4096, 256, 0, stream>>>(x, xb, 4194304 / 4);
  cast_f32_bf16<<<3072, 256, 0, stream>>>(w_qkv, wqkvb, 3145728 / 4);
  cast_f32_bf16<<<1024, 256, 0, stream>>>(w_out, woutb, 1048576 / 4);

  // 2. qkv = x @ w_qkv^T   (M=4096, N=3072, K=1024) -> bf16
  gemm_bt<1><<<dim3(24, 32), 256, 0, stream>>>(xb, wqkvb, qkvb, 4096, 3072, 1024);

  // 3. rope q,k -> (BH,S,64); 4. transpose v -> (BH,64,S)
  rope_qk<<<8192, 256, 0, stream>>>(qkvb, Qh, Kh);
  transpose_v<<<dim3(32, 32), 256, 0, stream>>>(qkvb, Vt);

  // 5. causal flash attention -> Ob (B,S,1024) bf16
  flash_attn<<<dim3(32, 32), 256, 0, stream>>>(Qh, Kh, Vt, Ob);

  // 6. out = Ob @ w_out^T  (M=4096, N=1024, K=1024) -> f32
  gemm_bt<0><<<dim3(8, 32), 256, 0, stream>>>(Ob, woutb, out, 4096, 1024, 1024);
}

// Round 2
// 201.889 us; speedup vs baseline: 1.0746x; 1.0746x over previous
//
#include <hip/hip_runtime.h>
#include <hip/hip_bf16.h>
#include <cstdint>

typedef __attribute__((ext_vector_type(8))) __bf16 bf16x8;
typedef __attribute__((ext_vector_type(4))) float f32x4;
typedef __attribute__((ext_vector_type(16))) float f32x16;

#define DM 1024
#define NH 16
#define DH 64
#define S_LEN 2048
#define BATCH 2

__device__ __forceinline__ ushort f2bf(float f) {
  union { float f; uint32_t u; } v; v.f = f;
  uint32_t u = v.u;
  uint32_t r = (u + 0x7fffu + ((u >> 16) & 1u)) >> 16;
  return (ushort)r;
}
__device__ __forceinline__ float bf2f(ushort h) {
  union { uint32_t u; float f; } v; v.u = ((uint32_t)h) << 16;
  return v.f;
}

__device__ __forceinline__ void gload16(const void* g, void* l) {
  __builtin_amdgcn_global_load_lds(
      (const __attribute__((address_space(1))) unsigned*)g,
      (__attribute__((address_space(3))) unsigned*)l, 16, 0, 0);
}

// ---------------- cast f32 -> bf16 ----------------
__global__ void cast_f32_bf16(const float* __restrict__ src, ushort* __restrict__ dst, int n4) {
  for (int i = blockIdx.x * blockDim.x + threadIdx.x; i < n4; i += gridDim.x * blockDim.x) {
    float4 v = ((const float4*)src)[i];
    ushort4 o;
    o.x = f2bf(v.x); o.y = f2bf(v.y); o.z = f2bf(v.z); o.w = f2bf(v.w);
    ((ushort4*)dst)[i] = o;
  }
}

// ---------------- GEMM: C[M,N] = A[M,K] * B[N,K]^T  (bf16 in, f32 acc) ----------------
template<int WRITE_BF16>
__global__ __launch_bounds__(256) void gemm_bt(
    const ushort* __restrict__ A, const ushort* __restrict__ B,
    void* __restrict__ Cv, int M, int N, int K)
{
  __shared__ ushort As[128][40];
  __shared__ ushort Bs[128][40];
  const int t = threadIdx.x;
  const int w = t >> 6, lane = t & 63;
  const int wm = w >> 1, wn = w & 1;
  const int lr = lane & 15, lk = lane >> 4;
  const int m0 = blockIdx.y * 128, n0 = blockIdx.x * 128;

  f32x4 acc[4][4];
#pragma unroll
  for (int m = 0; m < 4; m++)
#pragma unroll
    for (int n = 0; n < 4; n++) acc[m][n] = (f32x4)(0.0f);

  for (int k0 = 0; k0 < K; k0 += 32) {
#pragma unroll
    for (int p = 0; p < 2; p++) {
      int c = t + p * 256;
      int row = c >> 2;
      int col = (c & 3) * 8;
      *(uint4*)&As[row][col] = *(const uint4*)&A[(size_t)(m0 + row) * K + k0 + col];
      *(uint4*)&Bs[row][col] = *(const uint4*)&B[(size_t)(n0 + row) * K + k0 + col];
    }
    __syncthreads();
    bf16x8 af[4], bfr[4];
#pragma unroll
    for (int m = 0; m < 4; m++) af[m]  = *(const bf16x8*)&As[wm * 64 + m * 16 + lr][lk * 8];
#pragma unroll
    for (int n = 0; n < 4; n++) bfr[n] = *(const bf16x8*)&Bs[wn * 64 + n * 16 + lr][lk * 8];
#pragma unroll
    for (int m = 0; m < 4; m++)
#pragma unroll
      for (int n = 0; n < 4; n++)
        acc[m][n] = __builtin_amdgcn_mfma_f32_16x16x32_bf16(af[m], bfr[n], acc[m][n], 0, 0, 0);
    __syncthreads();
  }

#pragma unroll
  for (int m = 0; m < 4; m++) {
    int row = m0 + wm * 64 + m * 16 + lk * 4;
#pragma unroll
    for (int n = 0; n < 4; n++) {
      int col = n0 + wn * 64 + n * 16 + lr;
#pragma unroll
      for (int r = 0; r < 4; r++) {
        float val = acc[m][n][r];
        if (WRITE_BF16) ((ushort*)Cv)[(size_t)(row + r) * N + col] = f2bf(val);
        else            ((float*)Cv)[(size_t)(row + r) * N + col] = val;
      }
    }
  }
}

// ---------------- RoPE on q,k + repack to (BH, S, 64); scale folded into Q ----------------
__global__ void rope_qk(const ushort* __restrict__ qkv, ushort* __restrict__ Qh, ushort* __restrict__ Kh) {
  int idx = blockIdx.x * 256 + threadIdx.x;   // 2^21 total
  int i = idx & 31;
  int h = (idx >> 5) & 15;
  int s = (idx >> 9) & 2047;
  int b = idx >> 20;
  float inv = expf(-(float)i * (9.210340371976184f / 32.0f));
  float ang = (float)s * inv;
  float sn, cs;
  sincosf(ang, &sn, &cs);
  size_t base = ((size_t)(b * S_LEN + s)) * 3072 + h * 64 + 2 * i;
  float qr = bf2f(qkv[base]),        qi = bf2f(qkv[base + 1]);
  float kr = bf2f(qkv[base + 1024]), ki = bf2f(qkv[base + 1025]);
  float oqr = qr * cs - qi * sn, oqi = qr * sn + qi * cs;
  float okr = kr * cs - ki * sn, oki = kr * sn + ki * cs;
  const float scale = 0.125f;  // D^-0.5
  size_t ob = ((size_t)((b * NH + h) * S_LEN + s)) * 64 + 2 * i;
  Qh[ob] = f2bf(oqr * scale); Qh[ob + 1] = f2bf(oqi * scale);
  Kh[ob] = f2bf(okr);         Kh[ob + 1] = f2bf(oki);
}

// ---------------- V: (b,s,h,d) slice of qkv -> Vt (BH, 64, S) ----------------
__global__ __launch_bounds__(256) void transpose_v(const ushort* __restrict__ qkv, ushort* __restrict__ Vt) {
  __shared__ ushort tile[64][72];
  int st = blockIdx.x;
  int bh = blockIdx.y;
  int b = bh >> 4, h = bh & 15;
  int t = threadIdx.x;
#pragma unroll
  for (int p = 0; p < 2; p++) {
    int c = t + p * 256;
    int srow = c >> 3;
    int d8 = (c & 7) * 8;
    *(uint4*)&tile[srow][d8] =
        *(const uint4*)&qkv[((size_t)(b * S_LEN + st * 64 + srow)) * 3072 + 2048 + h * 64 + d8];
  }
  __syncthreads();
#pragma unroll
  for (int p = 0; p < 2; p++) {
    int c = t + p * 256;
    int d = c >> 3;
    int s8 = (c & 7) * 8;
    ushort tmp[8];
#pragma unroll
    for (int j = 0; j < 8; j++) tmp[j] = tile[s8 + j][d];
    *(uint4*)&Vt[((size_t)(bh * 64 + d)) * S_LEN + st * 64 + s8] = *(uint4*)tmp;
  }
}

// ---------------- causal flash attention v2 ----------------
// 2 waves/block, each wave: 32 q-rows via 32x32x16 mfma, swapped QK^T.
// K/V double-buffered in LDS via global_load_lds with XOR-swizzled source.
union SMemU {
  struct { ushort K[2][64][64]; ushort V[2][64][64]; } kv;  // 32 KB
  ushort Ot[64][68];                                        // epilogue alias
};

__global__ __launch_bounds__(128) void flash_attn2(
    const ushort* __restrict__ Qh, const ushort* __restrict__ Kh, const ushort* __restrict__ Vt,
    ushort* __restrict__ O)
{
  __shared__ __align__(16) SMemU sm;
  __shared__ __align__(16) ushort P4[2][16][34][4];  // per-wave P^T: [k>>2][q][k&3]

  const int qt = 31 - blockIdx.x;   // heavy tiles first
  const int bh = blockIdx.y;
  const int b = bh >> 4, h = bh & 15;
  const int t = threadIdx.x;
  const int w = t >> 6, lane = t & 63;
  const int q5 = lane & 31, hi = lane >> 5;

  // Q in registers: B-fragment of Q^T, 4 kd-chunks
  bf16x8 qreg[4];
  {
    const int qrow = qt * 64 + w * 32 + q5;
    const size_t qb = ((size_t)bh * S_LEN + qrow) * 64;
#pragma unroll
    for (int c = 0; c < 4; ++c)
      qreg[c] = *(const bf16x8*)&Qh[qb + c * 16 + hi * 8];
  }

  f32x16 oacc[2];
  oacc[0] = (f32x16)(0.0f); oacc[1] = (f32x16)(0.0f);
  float mrun = -1e30f, lsum = 0.0f;

  const ushort* Kg = &Kh[((size_t)bh * S_LEN) * 64];
  const ushort* Vg = &Vt[((size_t)bh * 64) * S_LEN];

  // stage K/V tile jt into buffer bf (each wave stages 32 rows of each)
  auto STAGE = [&](int bf, int jt) {
#pragma unroll
    for (int p = 0; p < 4; ++p) {
      int row = w * 32 + p * 8 + (lane >> 3);
      int c16 = (lane & 7) ^ (row & 7);
      gload16(&Kg[((size_t)(jt * 64 + row)) * 64 + c16 * 8], &sm.kv.K[bf][w * 32 + p * 8][0]);
      gload16(&Vg[((size_t)row) * S_LEN + jt * 64 + c16 * 8], &sm.kv.V[bf][w * 32 + p * 8][0]);
    }
  };

  STAGE(0, 0);
  __syncthreads();

  int cur = 0;
  for (int jt = 0; jt <= qt; ++jt) {
    if (jt < qt) STAGE(cur ^ 1, jt + 1);

    // ---- QK^T (swapped): sc[kg] = K-frag x Q^T-frag ----
    f32x16 sc[2];
    sc[0] = (f32x16)(0.0f); sc[1] = (f32x16)(0.0f);
    __builtin_amdgcn_s_setprio(1);
#pragma unroll
    for (int kg = 0; kg < 2; ++kg) {
      const int kr = kg * 32 + q5;
#pragma unroll
      for (int c = 0; c < 4; ++c) {
        bf16x8 kf = *(const bf16x8*)&sm.kv.K[cur][kr][((c * 2 + hi) ^ (kr & 7)) * 8];
        sc[kg] = __builtin_amdgcn_mfma_f32_32x32x16_bf16(kf, qreg[c], sc[kg], 0, 0, 0);
      }
    }
    __builtin_amdgcn_s_setprio(0);

    // ---- causal mask (diag tile only) ----
    if (jt == qt) {
      const int qloc = w * 32 + q5;
#pragma unroll
      for (int r = 0; r < 16; ++r) {
        const int kl = (r & 3) + 8 * (r >> 2) + 4 * hi;
        if (kl > qloc)      sc[0][r] = -1e30f;
        if (kl + 32 > qloc) sc[1][r] = -1e30f;
      }
    }

    // ---- online softmax, per-lane (one q-column per lane) ----
    float pmax = -1e30f;
#pragma unroll
    for (int r = 0; r < 16; ++r) { pmax = fmaxf(pmax, sc[0][r]); pmax = fmaxf(pmax, sc[1][r]); }
    pmax = fmaxf(pmax, __shfl_xor(pmax, 32, 64));
    const float mnew = fmaxf(mrun, pmax);
    const float alpha = __expf(mrun - mnew);
    mrun = mnew;
    float rsum = 0.0f;
#pragma unroll
    for (int kg = 0; kg < 2; ++kg)
#pragma unroll
      for (int r = 0; r < 16; ++r) { sc[kg][r] = __expf(sc[kg][r] - mnew); rsum += sc[kg][r]; }
    rsum += __shfl_xor(rsum, 32, 64);
    lsum = lsum * alpha + rsum;
#pragma unroll
    for (int r = 0; r < 16; ++r) { oacc[0][r] *= alpha; oacc[1][r] *= alpha; }

    // ---- write P^T to per-wave LDS (b64 quads) ----
#pragma unroll
    for (int kg = 0; kg < 2; ++kg)
#pragma unroll
      for (int g = 0; g < 4; ++g) {
        ushort4 pk;
        pk.x = f2bf(sc[kg][4 * g + 0]); pk.y = f2bf(sc[kg][4 * g + 1]);
        pk.z = f2bf(sc[kg][4 * g + 2]); pk.w = f2bf(sc[kg][4 * g + 3]);
        *(ushort4*)&P4[w][kg * 8 + g * 2 + hi][q5][0] = pk;
      }

    // ---- PV: O^T += V^T-frag x P^T-frag ----
    bf16x8 pf[4];
#pragma unroll
    for (int kc = 0; kc < 4; ++kc) {
      union { uint32_t u[4]; bf16x8 v; } cv;
      uint2 a = *(const uint2*)&P4[w][kc * 4 + hi * 2][q5][0];
      uint2 bq = *(const uint2*)&P4[w][kc * 4 + hi * 2 + 1][q5][0];
      cv.u[0] = a.x; cv.u[1] = a.y; cv.u[2] = bq.x; cv.u[3] = bq.y;
      pf[kc] = cv.v;
    }
    __builtin_amdgcn_s_setprio(1);
#pragma unroll
    for (int dg = 0; dg < 2; ++dg) {
      const int vr = dg * 32 + q5;
#pragma unroll
      for (int kc = 0; kc < 4; ++kc) {
        bf16x8 vf = *(const bf16x8*)&sm.kv.V[cur][vr][((kc * 2 + hi) ^ (vr & 7)) * 8];
        oacc[dg] = __builtin_amdgcn_mfma_f32_32x32x16_bf16(vf, pf[kc], oacc[dg], 0, 0, 0);
      }
    }
    __builtin_amdgcn_s_setprio(0);

    __syncthreads();
    cur ^= 1;
  }

  // ---- epilogue: O^T -> LDS transpose -> coalesced global store ----
  const float inv = 1.0f / lsum;
#pragma unroll
  for (int dg = 0; dg < 2; ++dg)
#pragma unroll
    for (int g = 0; g < 4; ++g) {
      ushort4 ok;
      ok.x = f2bf(oacc[dg][4 * g + 0] * inv); ok.y = f2bf(oacc[dg][4 * g + 1] * inv);
      ok.z = f2bf(oacc[dg][4 * g + 2] * inv); ok.w = f2bf(oacc[dg][4 * g + 3] * inv);
      *(ushort4*)&sm.Ot[w * 32 + q5][dg * 32 + g * 8 + 4 * hi] = ok;
    }
  __syncthreads();
  {
    const int row = t >> 1, c32 = (t & 1) * 32;
    const size_t gb = ((size_t)(b * S_LEN + qt * 64 + row)) * DM + h * 64 + c32;
#pragma unroll
    for (int j = 0; j < 4; ++j)
      *(uint4*)&O[gb + j * 8] = *(const uint4*)&sm.Ot[row][c32 + j * 8];
  }
}

extern "C" void kernel_launch(void* const* d_in, const int* in_sizes, int n_in,
                              void* d_out, int out_size, void* d_ws, size_t ws_size,
                              hipStream_t stream) {
  const float* x     = (const float*)d_in[0];
  const float* w_qkv = (const float*)d_in[2];
  const float* w_out = (const float*)d_in[3];
  float* out = (float*)d_out;

  char* ws = (char*)d_ws;
  ushort* xb    = (ushort*)(ws);
  ushort* wqkvb = (ushort*)(ws + 8388608);
  ushort* woutb = (ushort*)(ws + 14680064);
  ushort* qkvb  = (ushort*)(ws + 16777216);
  ushort* Qh    = (ushort*)(ws + 41943040);
  ushort* Kh    = (ushort*)(ws + 50331648);
  ushort* Vt    = (ushort*)(ws + 58720256);
  ushort* Ob    = (ushort*)(ws + 67108864);

  cast_f32_bf16<<<4096, 256, 0, stream>>>(x, xb, 4194304 / 4);
  cast_f32_bf16<<<3072, 256, 0, stream>>>(w_qkv, wqkvb, 3145728 / 4);
  cast_f32_bf16<<<1024, 256, 0, stream>>>(w_out, woutb, 1048576 / 4);

  gemm_bt<1><<<dim3(24, 32), 256, 0, stream>>>(xb, wqkvb, qkvb, 4096, 3072, 1024);

  rope_qk<<<8192, 256, 0, stream>>>(qkvb, Qh, Kh);
  transpose_v<<<dim3(32, 32), 256, 0, stream>>>(qkvb, Vt);

  flash_attn2<<<dim3(32, 32), 128, 0, stream>>>(Qh, Kh, Vt, Ob);

  gemm_bt<0><<<dim3(8, 32), 256, 0, stream>>>(Ob, woutb, out, 4096, 1024, 1024);
}

// Round 3
// 141.609 us; speedup vs baseline: 1.5320x; 1.4257x over previous
//
#include <hip/hip_runtime.h>
#include <hip/hip_bf16.h>
#include <cstdint>

typedef __attribute__((ext_vector_type(8))) __bf16 bf16x8;
typedef __attribute__((ext_vector_type(4))) float f32x4;
typedef __attribute__((ext_vector_type(16))) float f32x16;

#define DM 1024
#define NH 16
#define DH 64
#define S_LEN 2048
#define BATCH 2

__device__ __forceinline__ ushort f2bf(float f) {
  union { float f; uint32_t u; } v; v.f = f;
  uint32_t u = v.u;
  uint32_t r = (u + 0x7fffu + ((u >> 16) & 1u)) >> 16;
  return (ushort)r;
}
__device__ __forceinline__ float bf2f(ushort h) {
  union { uint32_t u; float f; } v; v.u = ((uint32_t)h) << 16;
  return v.f;
}

__device__ __forceinline__ void gload16(const void* g, void* l) {
  __builtin_amdgcn_global_load_lds(
      (const __attribute__((address_space(1))) unsigned*)g,
      (__attribute__((address_space(3))) unsigned*)l, 16, 0, 0);
}

// ---------------- cast f32 -> bf16 ----------------
__global__ void cast_f32_bf16(const float* __restrict__ src, ushort* __restrict__ dst, int n4) {
  for (int i = blockIdx.x * blockDim.x + threadIdx.x; i < n4; i += gridDim.x * blockDim.x) {
    float4 v = ((const float4*)src)[i];
    ushort4 o;
    o.x = f2bf(v.x); o.y = f2bf(v.y); o.z = f2bf(v.z); o.w = f2bf(v.w);
    ((ushort4*)dst)[i] = o;
  }
}

// ---------------- GEMM: C[M,N] = A[M,K] * B[N,K]^T  (bf16 in, f32 acc) ----------------
template<int WRITE_BF16>
__global__ __launch_bounds__(256) void gemm_bt(
    const ushort* __restrict__ A, const ushort* __restrict__ B,
    void* __restrict__ Cv, int M, int N, int K)
{
  __shared__ ushort As[128][40];
  __shared__ ushort Bs[128][40];
  const int t = threadIdx.x;
  const int w = t >> 6, lane = t & 63;
  const int wm = w >> 1, wn = w & 1;
  const int lr = lane & 15, lk = lane >> 4;
  const int m0 = blockIdx.y * 128, n0 = blockIdx.x * 128;

  f32x4 acc[4][4];
#pragma unroll
  for (int m = 0; m < 4; m++)
#pragma unroll
    for (int n = 0; n < 4; n++) acc[m][n] = (f32x4)(0.0f);

  for (int k0 = 0; k0 < K; k0 += 32) {
#pragma unroll
    for (int p = 0; p < 2; p++) {
      int c = t + p * 256;
      int row = c >> 2;
      int col = (c & 3) * 8;
      *(uint4*)&As[row][col] = *(const uint4*)&A[(size_t)(m0 + row) * K + k0 + col];
      *(uint4*)&Bs[row][col] = *(const uint4*)&B[(size_t)(n0 + row) * K + k0 + col];
    }
    __syncthreads();
    bf16x8 af[4], bfr[4];
#pragma unroll
    for (int m = 0; m < 4; m++) af[m]  = *(const bf16x8*)&As[wm * 64 + m * 16 + lr][lk * 8];
#pragma unroll
    for (int n = 0; n < 4; n++) bfr[n] = *(const bf16x8*)&Bs[wn * 64 + n * 16 + lr][lk * 8];
#pragma unroll
    for (int m = 0; m < 4; m++)
#pragma unroll
      for (int n = 0; n < 4; n++)
        acc[m][n] = __builtin_amdgcn_mfma_f32_16x16x32_bf16(af[m], bfr[n], acc[m][n], 0, 0, 0);
    __syncthreads();
  }

#pragma unroll
  for (int m = 0; m < 4; m++) {
    int row = m0 + wm * 64 + m * 16 + lk * 4;
#pragma unroll
    for (int n = 0; n < 4; n++) {
      int col = n0 + wn * 64 + n * 16 + lr;
#pragma unroll
      for (int r = 0; r < 4; r++) {
        float val = acc[m][n][r];
        if (WRITE_BF16) ((ushort*)Cv)[(size_t)(row + r) * N + col] = f2bf(val);
        else            ((float*)Cv)[(size_t)(row + r) * N + col] = val;
      }
    }
  }
}

// ---------------- RoPE on q,k + repack to (BH, S, 64) ----------------
// Q scale = D^-0.5 * log2(e): softmax runs in log2 domain downstream.
__global__ void rope_qk(const ushort* __restrict__ qkv, ushort* __restrict__ Qh, ushort* __restrict__ Kh) {
  int idx = blockIdx.x * 256 + threadIdx.x;
  int i = idx & 31;
  int h = (idx >> 5) & 15;
  int s = (idx >> 9) & 2047;
  int b = idx >> 20;
  float inv = expf(-(float)i * (9.210340371976184f / 32.0f));
  float ang = (float)s * inv;
  float sn, cs;
  sincosf(ang, &sn, &cs);
  size_t base = ((size_t)(b * S_LEN + s)) * 3072 + h * 64 + 2 * i;
  float qr = bf2f(qkv[base]),        qi = bf2f(qkv[base + 1]);
  float kr = bf2f(qkv[base + 1024]), ki = bf2f(qkv[base + 1025]);
  float oqr = qr * cs - qi * sn, oqi = qr * sn + qi * cs;
  float okr = kr * cs - ki * sn, oki = kr * sn + ki * cs;
  const float scale = 0.125f * 1.4426950408889634f;
  size_t ob = ((size_t)((b * NH + h) * S_LEN + s)) * 64 + 2 * i;
  Qh[ob] = f2bf(oqr * scale); Qh[ob + 1] = f2bf(oqi * scale);
  Kh[ob] = f2bf(okr);         Kh[ob + 1] = f2bf(oki);
}

// ---------------- V: (b,s,h,d) slice of qkv -> Vt (BH, 64, S) ----------------
__global__ __launch_bounds__(256) void transpose_v(const ushort* __restrict__ qkv, ushort* __restrict__ Vt) {
  __shared__ ushort tile[64][72];
  int st = blockIdx.x;
  int bh = blockIdx.y;
  int b = bh >> 4, h = bh & 15;
  int t = threadIdx.x;
#pragma unroll
  for (int p = 0; p < 2; p++) {
    int c = t + p * 256;
    int srow = c >> 3;
    int d8 = (c & 7) * 8;
    *(uint4*)&tile[srow][d8] =
        *(const uint4*)&qkv[((size_t)(b * S_LEN + st * 64 + srow)) * 3072 + 2048 + h * 64 + d8];
  }
  __syncthreads();
#pragma unroll
  for (int p = 0; p < 2; p++) {
    int c = t + p * 256;
    int d = c >> 3;
    int s8 = (c & 7) * 8;
    ushort tmp[8];
#pragma unroll
    for (int j = 0; j < 8; j++) tmp[j] = tile[s8 + j][d];
    *(uint4*)&Vt[((size_t)(bh * 64 + d)) * S_LEN + st * 64 + s8] = *(uint4*)tmp;
  }
}

// ---------------- causal flash attention v3 ----------------
// 2 waves/block, 32 q-rows/wave via 32x32x16 mfma (swapped QK^T).
// P kept in registers via cvt_pk_bf16 + permlane32_swap (T12). LDS = 32 KB
// (K/V double-buffer only) -> 5 blocks/CU. Softmax in log2 domain, defer-max (T13).
union SMemU {
  struct { ushort K[2][64][64]; ushort V[2][64][64]; } kv;  // 32 KB
  ushort Ot[64][68];                                        // epilogue alias
};

__global__ __launch_bounds__(128) void flash_attn3(
    const ushort* __restrict__ Qh, const ushort* __restrict__ Kh, const ushort* __restrict__ Vt,
    ushort* __restrict__ O)
{
  __shared__ __align__(16) SMemU sm;

  const int bh = blockIdx.x;        // x = bh: XCD = bh%8 -> 4 bh per XCD L2
  const int qt = 31 - blockIdx.y;   // heavy q-tiles dispatched first
  const int b = bh >> 4, h = bh & 15;
  const int t = threadIdx.x;
  const int w = t >> 6, lane = t & 63;
  const int q5 = lane & 31, hi = lane >> 5;

  bf16x8 qreg[4];
  {
    const int qrow = qt * 64 + w * 32 + q5;
    const size_t qb = ((size_t)bh * S_LEN + qrow) * 64;
#pragma unroll
    for (int c = 0; c < 4; ++c)
      qreg[c] = *(const bf16x8*)&Qh[qb + c * 16 + hi * 8];
  }

  f32x16 oacc[2];
  oacc[0] = (f32x16)(0.0f); oacc[1] = (f32x16)(0.0f);
  float mrun = -1e30f, lsum = 0.0f;

  const ushort* Kg = &Kh[((size_t)bh * S_LEN) * 64];
  const ushort* Vg = &Vt[((size_t)bh * 64) * S_LEN];

  auto STAGE = [&](int bf, int jt) {
#pragma unroll
    for (int p = 0; p < 4; ++p) {
      int row = w * 32 + p * 8 + (lane >> 3);
      int c16 = (lane & 7) ^ (row & 7);
      gload16(&Kg[((size_t)(jt * 64 + row)) * 64 + c16 * 8], &sm.kv.K[bf][w * 32 + p * 8][0]);
      gload16(&Vg[((size_t)row) * S_LEN + jt * 64 + c16 * 8], &sm.kv.V[bf][w * 32 + p * 8][0]);
    }
  };

  STAGE(0, 0);
  __syncthreads();

  int cur = 0;
  for (int jt = 0; jt <= qt; ++jt) {
    if (jt < qt) STAGE(cur ^ 1, jt + 1);

    // ---- QK^T (swapped): sc = K-frag x Q^T-frag; lane holds P-row slice ----
    f32x16 sc[2];
    sc[0] = (f32x16)(0.0f); sc[1] = (f32x16)(0.0f);
    __builtin_amdgcn_s_setprio(1);
#pragma unroll
    for (int kg = 0; kg < 2; ++kg) {
      const int kr = kg * 32 + q5;
#pragma unroll
      for (int c = 0; c < 4; ++c) {
        bf16x8 kf = *(const bf16x8*)&sm.kv.K[cur][kr][((c * 2 + hi) ^ (kr & 7)) * 8];
        sc[kg] = __builtin_amdgcn_mfma_f32_32x32x16_bf16(kf, qreg[c], sc[kg], 0, 0, 0);
      }
    }
    __builtin_amdgcn_s_setprio(0);

    // ---- causal mask (diag tile only) ----
    if (jt == qt) {
      const int qloc = w * 32 + q5;
#pragma unroll
      for (int r = 0; r < 16; ++r) {
        const int kl = (r & 3) + 8 * (r >> 2) + 4 * hi;
        if (kl > qloc)      sc[0][r] = -1e30f;
        if (kl + 32 > qloc) sc[1][r] = -1e30f;
      }
    }

    // ---- online softmax (log2 domain), defer-max T13 ----
    float pmax = -1e30f;
#pragma unroll
    for (int r = 0; r < 16; ++r) { pmax = fmaxf(pmax, sc[0][r]); pmax = fmaxf(pmax, sc[1][r]); }
    pmax = fmaxf(pmax, __shfl_xor(pmax, 32, 64));
    if (!__all(pmax - mrun <= 8.0f)) {
      const float mnew = fmaxf(mrun, pmax);
      const float alpha = __builtin_amdgcn_exp2f(mrun - mnew);
      mrun = mnew;
      lsum *= alpha;
#pragma unroll
      for (int r = 0; r < 16; ++r) { oacc[0][r] *= alpha; oacc[1][r] *= alpha; }
    }
    float rsum = 0.0f;
#pragma unroll
    for (int kg = 0; kg < 2; ++kg)
#pragma unroll
      for (int r = 0; r < 16; ++r) {
        sc[kg][r] = __builtin_amdgcn_exp2f(sc[kg][r] - mrun);
        rsum += sc[kg][r];
      }
    rsum += __shfl_xor(rsum, 32, 64);
    lsum += rsum;

    // ---- P -> bf16 B-fragments in registers (T12: cvt_pk + permlane32_swap) ----
    bf16x8 pf[4];
#pragma unroll
    for (int kc = 0; kc < 4; ++kc) {
      const int kg = kc >> 1, rA = (kc & 1) * 8, rB = rA + 4;
      uint32_t A0, A1, B0, B1;
      asm("v_cvt_pk_bf16_f32 %0, %1, %2" : "=v"(A0) : "v"(sc[kg][rA + 0]), "v"(sc[kg][rA + 1]));
      asm("v_cvt_pk_bf16_f32 %0, %1, %2" : "=v"(A1) : "v"(sc[kg][rA + 2]), "v"(sc[kg][rA + 3]));
      asm("v_cvt_pk_bf16_f32 %0, %1, %2" : "=v"(B0) : "v"(sc[kg][rB + 0]), "v"(sc[kg][rB + 1]));
      asm("v_cvt_pk_bf16_f32 %0, %1, %2" : "=v"(B1) : "v"(sc[kg][rB + 2]), "v"(sc[kg][rB + 3]));
      asm("v_permlane32_swap_b32 %0, %1" : "+v"(A0), "+v"(B0));
      asm("v_permlane32_swap_b32 %0, %1" : "+v"(A1), "+v"(B1));
      union { uint32_t u[4]; bf16x8 v; } cv;
      cv.u[0] = A0; cv.u[1] = A1; cv.u[2] = B0; cv.u[3] = B1;
      pf[kc] = cv.v;
    }

    // ---- PV: O^T += V^T-frag x P^T-frag ----
    __builtin_amdgcn_s_setprio(1);
#pragma unroll
    for (int dg = 0; dg < 2; ++dg) {
      const int vr = dg * 32 + q5;
#pragma unroll
      for (int kc = 0; kc < 4; ++kc) {
        bf16x8 vf = *(const bf16x8*)&sm.kv.V[cur][vr][((kc * 2 + hi) ^ (vr & 7)) * 8];
        oacc[dg] = __builtin_amdgcn_mfma_f32_32x32x16_bf16(vf, pf[kc], oacc[dg], 0, 0, 0);
      }
    }
    __builtin_amdgcn_s_setprio(0);

    __syncthreads();
    cur ^= 1;
  }

  // ---- epilogue: O^T -> LDS transpose -> coalesced global store ----
  const float inv = 1.0f / lsum;
#pragma unroll
  for (int dg = 0; dg < 2; ++dg)
#pragma unroll
    for (int g = 0; g < 4; ++g) {
      ushort4 ok;
      ok.x = f2bf(oacc[dg][4 * g + 0] * inv); ok.y = f2bf(oacc[dg][4 * g + 1] * inv);
      ok.z = f2bf(oacc[dg][4 * g + 2] * inv); ok.w = f2bf(oacc[dg][4 * g + 3] * inv);
      *(ushort4*)&sm.Ot[w * 32 + q5][dg * 32 + g * 8 + 4 * hi] = ok;
    }
  __syncthreads();
  {
    const int row = t >> 1, c32 = (t & 1) * 32;
    const size_t gb = ((size_t)(b * S_LEN + qt * 64 + row)) * DM + h * 64 + c32;
#pragma unroll
    for (int j = 0; j < 4; ++j)
      *(uint4*)&O[gb + j * 8] = *(const uint4*)&sm.Ot[row][c32 + j * 8];
  }
}

extern "C" void kernel_launch(void* const* d_in, const int* in_sizes, int n_in,
                              void* d_out, int out_size, void* d_ws, size_t ws_size,
                              hipStream_t stream) {
  const float* x     = (const float*)d_in[0];
  const float* w_qkv = (const float*)d_in[2];
  const float* w_out = (const float*)d_in[3];
  float* out = (float*)d_out;

  char* ws = (char*)d_ws;
  ushort* xb    = (ushort*)(ws);
  ushort* wqkvb = (ushort*)(ws + 8388608);
  ushort* woutb = (ushort*)(ws + 14680064);
  ushort* qkvb  = (ushort*)(ws + 16777216);
  ushort* Qh    = (ushort*)(ws + 41943040);
  ushort* Kh    = (ushort*)(ws + 50331648);
  ushort* Vt    = (ushort*)(ws + 58720256);
  ushort* Ob    = (ushort*)(ws + 67108864);

  cast_f32_bf16<<<4096, 256, 0, stream>>>(x, xb, 4194304 / 4);
  cast_f32_bf16<<<3072, 256, 0, stream>>>(w_qkv, wqkvb, 3145728 / 4);
  cast_f32_bf16<<<1024, 256, 0, stream>>>(w_out, woutb, 1048576 / 4);

  gemm_bt<1><<<dim3(24, 32), 256, 0, stream>>>(xb, wqkvb, qkvb, 4096, 3072, 1024);

  rope_qk<<<8192, 256, 0, stream>>>(qkvb, Qh, Kh);
  transpose_v<<<dim3(32, 32), 256, 0, stream>>>(qkvb, Vt);

  // grid: x = bh (32), y = qtile (32, heavy-first)
  flash_attn3<<<dim3(32, 32), 128, 0, stream>>>(Qh, Kh, Vt, Ob);

  gemm_bt<0><<<dim3(8, 32), 256, 0, stream>>>(Ob, woutb, out, 4096, 1024, 1024);
}